// Round 2
// baseline (251.773 us; speedup 1.0000x reference)
//
#include <hip/hip_runtime.h>

// Laplace transform forward: out[n,i,f] = e[i]*out[n-1,i,f] + decay[i]*inp[n,f]
// T=2048, F=256, N_S=108. float32 in / float32 out (per reference dtypes).
//
// Math: e[i] = exp(-4/tau_star[i]) <= exp(-4/22.574) = 0.8376, so e^64 ~ 1.2e-5.
// Contributions older than 64 steps are < ~1e-4 absolute (threshold 0.1625).
// => time-parallel: each chunk of 128 steps warms up 64 steps from zero state.

#define T_LEN 2048
#define F_DIM 256
#define NS    108      // NTAU + 2*K = 100 + 8
#define KPAD  4
#define CHUNK 128
#define WARM  64

__global__ __launch_bounds__(256) void laplace_kernel(
    const float* __restrict__ inp,   // (T, F) f32
    float* __restrict__ out)         // (T, NS, F) f32
{
    const int tid  = threadIdx.x;
    const int lane = tid & 63;                       // 64 lanes cover 256 features x4
    const int f0   = lane * 4;
    const int i    = blockIdx.y * 4 + (tid >> 6);    // taustar index (4 per block)
    const int n0   = blockIdx.x * CHUNK;             // time chunk start

    // per-taustar constants (once per thread; tolerance is ~2% so powf/expf fine)
    const float c     = powf(20.0f, 1.0f / 99.0f) - 1.0f;
    const float tau   = powf(1.0f + c, (float)(i - KPAD));
    const float s     = 4.0f / tau;
    const float e     = expf(-s);
    const float decay = (1.0f - e) / s;

    const float* ip = inp + f0;

    float t0 = 0.0f, t1 = 0.0f, t2 = 0.0f, t3 = 0.0f;

    // warm-up: recover state from the previous WARM inputs (zero init exact for
    // chunk 0; error <= e^WARM * |t| ~ 1e-4 otherwise)
    int nstart = n0 - WARM;
    if (nstart < 0) nstart = 0;
    for (int n = nstart; n < n0; ++n) {
        float4 x = *(const float4*)(ip + (size_t)n * F_DIM);
        t0 = fmaf(e, t0, decay * x.x);
        t1 = fmaf(e, t1, decay * x.y);
        t2 = fmaf(e, t2, decay * x.z);
        t3 = fmaf(e, t3, decay * x.w);
    }

    // main: compute and store CHUNK outputs
    float* op = out + (size_t)i * F_DIM + f0;
    for (int n = n0; n < n0 + CHUNK; ++n) {
        float4 x = *(const float4*)(ip + (size_t)n * F_DIM);
        t0 = fmaf(e, t0, decay * x.x);
        t1 = fmaf(e, t1, decay * x.y);
        t2 = fmaf(e, t2, decay * x.z);
        t3 = fmaf(e, t3, decay * x.w);
        float4 r; r.x = t0; r.y = t1; r.z = t2; r.w = t3;
        *(float4*)(op + (size_t)n * (NS * F_DIM)) = r;
    }
}

extern "C" void kernel_launch(void* const* d_in, const int* in_sizes, int n_in,
                              void* d_out, int out_size, void* d_ws, size_t ws_size,
                              hipStream_t stream) {
    const float* inp = (const float*)d_in[0];
    float* out = (float*)d_out;

    dim3 grid(T_LEN / CHUNK, NS / 4);   // 16 x 27 = 432 blocks
    laplace_kernel<<<grid, 256, 0, stream>>>(inp, out);
}

// Round 4
// 237.322 us; speedup vs baseline: 1.0609x; 1.0609x over previous
//
#include <hip/hip_runtime.h>

// Laplace transform forward: out[n,i,f] = e[i]*out[n-1,i,f] + decay[i]*inp[n,f]
// T=2048, F=256, N_S=108. float32 in / float32 out.
//
// Time-parallel: e[i] <= exp(-4/22.574) = 0.8376 => e^48 ~ 2e-4; contributions
// older than 48 steps are < ~6e-3 absolute (threshold 0.1625, measured margin
// 5x at WARM=64). Each chunk of 64 outputs warms up 48 steps from zero state.
//
// R2 post-mortem: 432 blocks = 1.7 waves/SIMD was latency-bound (~2 TB/s eff;
// the harness's own 906MB fill does 6.6 TB/s on the same buffer). CHUNK 128->64
// doubles TLP; nontemporal stores keep L2 for the input rereads.

#define T_LEN 2048
#define F_DIM 256
#define NS    108      // NTAU + 2*K = 100 + 8
#define KPAD  4
#define CHUNK 64
#define WARM  48

typedef float f32x4 __attribute__((ext_vector_type(4)));  // native vector: ok for nontemporal builtin

__global__ __launch_bounds__(256) void laplace_kernel(
    const float* __restrict__ inp,   // (T, F) f32
    float* __restrict__ out)         // (T, NS, F) f32
{
    const int tid  = threadIdx.x;
    const int lane = tid & 63;                       // 64 lanes x float4 = 256 features
    const int f0   = lane * 4;
    const int i    = blockIdx.y * 4 + (tid >> 6);    // taustar index (4 per block)
    const int n0   = blockIdx.x * CHUNK;             // time chunk start

    // per-taustar constants (once per thread; ~2% tolerance, powf/expf fine)
    const float c     = powf(20.0f, 1.0f / 99.0f) - 1.0f;
    const float tau   = powf(1.0f + c, (float)(i - KPAD));
    const float s     = 4.0f / tau;
    const float e     = expf(-s);
    const float decay = (1.0f - e) / s;

    const float* ip = inp + f0;

    float t0 = 0.0f, t1 = 0.0f, t2 = 0.0f, t3 = 0.0f;

    // warm-up: recover state from the previous WARM inputs (exact for chunk 0)
    int nstart = n0 - WARM;
    if (nstart < 0) nstart = 0;
    #pragma unroll 4
    for (int n = nstart; n < n0; ++n) {
        f32x4 x = *(const f32x4*)(ip + (size_t)n * F_DIM);
        t0 = fmaf(e, t0, decay * x.x);
        t1 = fmaf(e, t1, decay * x.y);
        t2 = fmaf(e, t2, decay * x.z);
        t3 = fmaf(e, t3, decay * x.w);
    }

    // main: compute and store CHUNK outputs (nontemporal — never reread)
    float* op = out + (size_t)i * F_DIM + f0;
    #pragma unroll 4
    for (int n = n0; n < n0 + CHUNK; ++n) {
        f32x4 x = *(const f32x4*)(ip + (size_t)n * F_DIM);
        t0 = fmaf(e, t0, decay * x.x);
        t1 = fmaf(e, t1, decay * x.y);
        t2 = fmaf(e, t2, decay * x.z);
        t3 = fmaf(e, t3, decay * x.w);
        f32x4 r; r.x = t0; r.y = t1; r.z = t2; r.w = t3;
        __builtin_nontemporal_store(r, (f32x4*)(op + (size_t)n * (NS * F_DIM)));
    }
}

extern "C" void kernel_launch(void* const* d_in, const int* in_sizes, int n_in,
                              void* d_out, int out_size, void* d_ws, size_t ws_size,
                              hipStream_t stream) {
    const float* inp = (const float*)d_in[0];
    float* out = (float*)d_out;

    dim3 grid(T_LEN / CHUNK, NS / 4);   // 32 x 27 = 864 blocks, 13.5 waves/CU
    laplace_kernel<<<grid, 256, 0, stream>>>(inp, out);
}